// Round 7
// baseline (162.528 us; speedup 1.0000x reference)
//
#include <hip/hip_runtime.h>
#include <hip/hip_bf16.h>

// B,C,H,W = 4,64,64,64 ; N = 4096 ; d = 8
#define BB 4
#define CC 64
#define NN 4096

typedef __attribute__((ext_vector_type(8))) short short8;
typedef __attribute__((ext_vector_type(4))) float f32x4;

__device__ inline ushort f2bf(float x) {                 // RNE float->bf16
    unsigned u = __float_as_uint(x);
    return (ushort)((u + 0x7fff + ((u >> 16) & 1)) >> 16);
}
__device__ inline float bf2f(ushort h) { return __uint_as_float(((unsigned)h) << 16); }

// ws layout (ushort):
//   qTp [B][N][32] : q0..q7, q0h,q1h,q0l,q1l, 0*20               (1 MB)
//   kTp [B][N][32] : k0..k7, col,row,col,row, 0*20               (1 MB)
//   vtb [B][64t][64j][64c] row-major bf16 V, REWRITTEN IN PLACE by
//       pack_kernel into B-frag chunks [tile 4096 halves]:
//       chunk cid = (s*4+g)*64 + quad*16 + nn holds v[j=s*32+quad*8+jj][c=16g+nn]
//       (identical bytes-per-tile layout attn has read since R4)    (2 MB)
//   kmax [B][8] fp32-bits as SIGNED int atomicMax (0xAA poison is negative)

// ---------------------------------------------------------------------------
// Kernel 1: QKV projection, R2-clone store scheme. 320 blocks x 256 threads.
// Blocks 0..255  (v path): (gid, eblk): 16 block-uniform v-rows x 1 px/thread,
//   stored as plain row-major bf16 [b][n][eblk*16..+15] = 2 uint4/thread.
// Blocks 256..319 (qk path): per-thread 8q+8k dots (compile-const rows ->
//   scalar weights), records built in-register, 4+4 uint4 stores + kmax.
// ---------------------------------------------------------------------------
__global__ __launch_bounds__(256) void qkv_kernel(
    const float* __restrict__ x,
    const float* __restrict__ Wq, const float* __restrict__ bq,
    const float* __restrict__ Wk, const float* __restrict__ bk,
    const float* __restrict__ Wv, const float* __restrict__ bv,
    ushort* __restrict__ qTp, ushort* __restrict__ kTp,
    ushort* __restrict__ vtb, int* __restrict__ kmax)
{
    const int blk = blockIdx.x, tid = threadIdx.x;

    if (blk < 256) {
        // ---------------- v path (R2 structure, bf16 stores) ----------------
        const int eblk = blk & 3;
        const int idx  = (blk >> 2) * 256 + tid;     // b*N + n
        const int b = idx >> 12, n = idx & (NN - 1);

        const float* xb = x + (size_t)(b * CC) * NN + n;
        float xc[CC];
#pragma unroll
        for (int c = 0; c < CC; ++c) xc[c] = xb[(size_t)c * NN];

        ushort h[16] __attribute__((aligned(16)));
#pragma unroll
        for (int r = 0; r < 16; ++r) {
            const int e = eblk * 16 + r;             // block-uniform row
            const float* wr = Wv + e * CC;
            float a = bv[e];
#pragma unroll
            for (int c = 0; c < CC; ++c) a += wr[c] * xc[c];
            h[r] = f2bf(a);
        }
        uint4* dst = (uint4*)(vtb + (size_t)(b * NN + n) * 64 + eblk * 16);
        dst[0] = ((const uint4*)h)[0];
        dst[1] = ((const uint4*)h)[1];
        return;
    }

    // ---------------- qk path ----------------
    const int idx = (blk - 256) * 256 + tid;     // b*N + n
    const int b = idx >> 12, n = idx & (NN - 1);
    const int px = n & 63, t = n >> 6;

    const float* xb = x + (size_t)(b * CC) * NN + n;
    float xv[CC];
#pragma unroll
    for (int c = 0; c < CC; ++c) xv[c] = xb[(size_t)c * NN];

    float s[16];
#pragma unroll
    for (int r = 0; r < 16; ++r) {               // r compile-const -> scalar weights
        const float* wr = (r < 8) ? (Wq + r * CC) : (Wk + (r - 8) * CC);
        float a = (r < 8) ? bq[r] : bk[r - 8];
#pragma unroll
        for (int c = 0; c < CC; ++c) a += wr[c] * xv[c];
        s[r] = a;
    }

    ushort hq[16] __attribute__((aligned(16))), hk[16] __attribute__((aligned(16)));
#pragma unroll
    for (int d = 0; d < 8; ++d) { hq[d] = f2bf(s[d]); hk[d] = f2bf(s[8 + d]); }
    hq[8]  = hq[0];  hq[9]  = hq[1];
    hq[10] = f2bf(s[0] - bf2f(hq[0]));
    hq[11] = f2bf(s[1] - bf2f(hq[1]));
    const ushort hc = f2bf((float)px), hr = f2bf((float)t);
    hk[8] = hc; hk[9] = hr; hk[10] = hc; hk[11] = hr;
#pragma unroll
    for (int i = 12; i < 16; ++i) { hq[i] = 0; hk[i] = 0; }

    const uint4 z = {0u, 0u, 0u, 0u};
    uint4* dq = (uint4*)(qTp + (size_t)(b * NN + n) * 32);
    uint4* dk = (uint4*)(kTp + (size_t)(b * NN + n) * 32);
    dq[0] = ((const uint4*)hq)[0]; dq[1] = ((const uint4*)hq)[1]; dq[2] = z; dq[3] = z;
    dk[0] = ((const uint4*)hk)[0]; dk[1] = ((const uint4*)hk)[1]; dk[2] = z; dk[3] = z;

    // per-batch |k_d| max of bf16-rounded values; signed-int atomicMax
#pragma unroll
    for (int d = 0; d < 8; ++d) {
        float kv = fabsf(bf2f(hk[d]));
#pragma unroll
        for (int off = 1; off < 64; off <<= 1) kv = fmaxf(kv, __shfl_xor(kv, off, 64));
        if ((tid & 63) == 0) atomicMax(kmax + b * 8 + d, (int)__float_as_uint(kv));
    }
}

// ---------------------------------------------------------------------------
// Kernel 1b: in-place V swizzle. 256 blocks = (b,t), 256 threads.
// Reads the 8 KB row-major tile fully into LDS, barrier, rewrites the SAME
// 8 KB in B-frag chunk order. Block only touches its own tile -> no races.
// ---------------------------------------------------------------------------
__global__ __launch_bounds__(256) void pack_kernel(ushort* vtb)
{
    const int b = blockIdx.x >> 6, t = blockIdx.x & 63;
    const int tid = threadIdx.x;
    __shared__ ushort vls[64 * 72];              // [j][c], stride 72 halves

    ushort* tile = vtb + (size_t)(b * 64 + t) * 4096;   // halves

    // phase 1: coalesced read [j][c] -> LDS
    const int j = tid >> 2, cq = tid & 3;
    const uint4 r0 = *(const uint4*)(tile + j * 64 + cq * 16);
    const uint4 r1 = *(const uint4*)(tile + j * 64 + cq * 16 + 8);
    *(uint4*)(vls + j * 72 + cq * 16)     = r0;
    *(uint4*)(vls + j * 72 + cq * 16 + 8) = r1;
    __syncthreads();

    // phase 2: chunk gather -> in-place coalesced uint4 stores
#pragma unroll
    for (int i = 0; i < 2; ++i) {
        const int cid = tid + i * 256;           // 0..511
        const int nn = cid & 15, quad = (cid >> 4) & 3, sg = cid >> 6;
        const int s = sg >> 2, g = sg & 3;
        const int j0 = s * 32 + quad * 8, c = g * 16 + nn;
        ushort h[8] __attribute__((aligned(16)));
#pragma unroll
        for (int jj = 0; jj < 8; ++jj) h[jj] = vls[(j0 + jj) * 72 + c];
        *(uint4*)(tile + (size_t)cid * 8) = ((const uint4*)h)[0];
    }
}

// ---------------------------------------------------------------------------
// Kernel 2: single-pass MFMA attention (UNCHANGED from R6).
// ---------------------------------------------------------------------------
__global__ __launch_bounds__(512, 4) void attn_kernel(
    const ushort* __restrict__ qTp, const ushort* __restrict__ kTp,
    const ushort* __restrict__ vsw, const int* __restrict__ kmaxi,
    float* __restrict__ out)
{
    const int blk = blockIdx.x;
    const int b  = (blk & 7) >> 1;                         // XCD-pair batch
    const int nq = (((blk >> 3) << 1) | (blk & 1)) * 32;   // query tile 0..127
    const int tid = threadIdx.x, wv = tid >> 6, lane = tid & 63;
    const int nn = lane & 15, quad = lane >> 4;

    __shared__ float obuf[32 * 81];      // [q][81]: ch 0..63 = out, 64 = den
    for (int i = tid; i < 32 * 81; i += 512) obuf[i] = 0.f;

    short8 qf[2];
    qf[0] = *(const short8*)(qTp + (size_t)(b * NN + nq + nn) * 32 + quad * 8);
    qf[1] = *(const short8*)(qTp + (size_t)(b * NN + nq + 16 + nn) * 32 + quad * 8);

    float Mq[2];
    {
        const int* kmax = kmaxi + b * 8;
#pragma unroll
        for (int qg = 0; qg < 2; ++qg) {
            float B1 = 0.f;
#pragma unroll
            for (int d = 0; d < 8; ++d)
                B1 += fabsf(bf2f((ushort)qf[qg][d])) * __uint_as_float((unsigned)kmax[d]);
            const float q0 = bf2f((ushort)qf[qg][0]) + bf2f((ushort)qf[qg][2]);
            const float q1 = bf2f((ushort)qf[qg][1]) + bf2f((ushort)qf[qg][3]);
            const float rel = fmaxf(q0 * 63.f, 0.f) + fmaxf(q1 * 63.f, 0.f);
            const float z  = (quad == 0) ? B1 : ((quad == 1) ? rel : 0.f);
            const float r1 = __shfl_xor(z, 16, 64);
            const float myB1  = (quad == 0) ? z : r1;
            const float myRel = (quad == 0) ? r1 : z;
            float f = myRel + fmaxf(myB1 - 20.f, 0.f) + 1.f;
            f = (quad < 2) ? f : 0.f;
            Mq[qg] = f + __shfl_xor(f, 32, 64);
        }
    }

    f32x4 acc[2][4];
#pragma unroll
    for (int qg = 0; qg < 2; ++qg)
#pragma unroll
        for (int g = 0; g < 4; ++g) acc[qg][g] = (f32x4){0.f, 0.f, 0.f, 0.f};
    float den[2] = {0.f, 0.f};

    const ushort* kb  = kTp + (size_t)b * NN * 32;
    const ushort* vb0 = vsw + (size_t)b * 64 * 4096;
    const int addr0 = (((quad & 1) * 2 + 0) * 16 + nn) * 4;
    const int addr1 = (((quad & 1) * 2 + 1) * 16 + nn) * 4;
    const int hi = quad >> 1;

    __syncthreads();

    for (int it = 0; it < 8; ++it) {
        const int t = wv + it * 8;

        short8 kf[4];
#pragma unroll
        for (int kg = 0; kg < 4; ++kg)
            kf[kg] = *(const short8*)(kb + (size_t)(t * 64 + kg * 16 + nn) * 32 + quad * 8);
        const ushort* vt0 = vb0 + (size_t)t * 4096;
        short8 vf[2][4];
#pragma unroll
        for (int s = 0; s < 2; ++s)
#pragma unroll
            for (int g = 0; g < 4; ++g)
                vf[s][g] = *(const short8*)(vt0 + (size_t)((s * 4 + g) * 64 + lane) * 8);

        uint2 pk[2][4];
#pragma unroll
        for (int qg = 0; qg < 2; ++qg) {
#pragma unroll
            for (int kg = 0; kg < 4; ++kg) {
                f32x4 S = __builtin_amdgcn_mfma_f32_16x16x32_bf16(
                    kf[kg], qf[qg], (f32x4){0.f, 0.f, 0.f, 0.f}, 0, 0, 0);
                const float w0 = __expf(S[0] - Mq[qg]);
                const float w1 = __expf(S[1] - Mq[qg]);
                const float w2 = __expf(S[2] - Mq[qg]);
                const float w3 = __expf(S[3] - Mq[qg]);
                den[qg] += (w0 + w1) + (w2 + w3);
                union { __hip_bfloat162 h; unsigned u; } pa, pb;
                pa.h = __float22bfloat162_rn(make_float2(w0, w1));
                pb.h = __float22bfloat162_rn(make_float2(w2, w3));
                pk[qg][kg].x = pa.u; pk[qg][kg].y = pb.u;
            }
        }

#pragma unroll
        for (int s = 0; s < 2; ++s) {
#pragma unroll
            for (int qg = 0; qg < 2; ++qg) {
                const uint2 pkA = pk[qg][2 * s], pkB = pk[qg][2 * s + 1];
                union { uint4 u; short8 h; } af;
                {
                    const int r0 = __builtin_amdgcn_ds_bpermute(addr0, (int)pkA.x);
                    const int r1 = __builtin_amdgcn_ds_bpermute(addr0, (int)pkB.x);
                    af.u.x = (unsigned)(hi ? r1 : r0);
                }
                {
                    const int r0 = __builtin_amdgcn_ds_bpermute(addr0, (int)pkA.y);
                    const int r1 = __builtin_amdgcn_ds_bpermute(addr0, (int)pkB.y);
                    af.u.y = (unsigned)(hi ? r1 : r0);
                }
                {
                    const int r0 = __builtin_amdgcn_ds_bpermute(addr1, (int)pkA.x);
                    const int r1 = __builtin_amdgcn_ds_bpermute(addr1, (int)pkB.x);
                    af.u.z = (unsigned)(hi ? r1 : r0);
                }
                {
                    const int r0 = __builtin_amdgcn_ds_bpermute(addr1, (int)pkA.y);
                    const int r1 = __builtin_amdgcn_ds_bpermute(addr1, (int)pkB.y);
                    af.u.w = (unsigned)(hi ? r1 : r0);
                }
#pragma unroll
                for (int g = 0; g < 4; ++g)
                    acc[qg][g] = __builtin_amdgcn_mfma_f32_16x16x32_bf16(af.h, vf[s][g], acc[qg][g], 0, 0, 0);
            }
        }
    }

#pragma unroll
    for (int qg = 0; qg < 2; ++qg) {
        float d = den[qg];
        d += __shfl_xor(d, 16, 64);
        d += __shfl_xor(d, 32, 64);
        if (lane < 16) atomicAdd(&obuf[(qg * 16 + lane) * 81 + 64], d);
    }
#pragma unroll
    for (int qg = 0; qg < 2; ++qg)
#pragma unroll
        for (int g = 0; g < 4; ++g)
#pragma unroll
            for (int r = 0; r < 4; ++r)
                atomicAdd(&obuf[(qg * 16 + quad * 4 + r) * 81 + g * 16 + nn], acc[qg][g][r]);
    __syncthreads();

    {
        const int q = tid & 31, c0 = tid >> 5;
#pragma unroll
        for (int i = 0; i < 4; ++i) {
            const int c = c0 + i * 16;
            out[(size_t)(b * CC + c) * NN + nq + q] = obuf[q * 81 + c] / obuf[q * 81 + 64];
        }
    }
}

extern "C" void kernel_launch(void* const* d_in, const int* in_sizes, int n_in,
                              void* d_out, int out_size, void* d_ws, size_t ws_size,
                              hipStream_t stream) {
    const float* x  = (const float*)d_in[0];
    const float* Wq = (const float*)d_in[1];
    const float* bq = (const float*)d_in[2];
    const float* Wk = (const float*)d_in[3];
    const float* bk = (const float*)d_in[4];
    const float* Wv = (const float*)d_in[5];
    const float* bv = (const float*)d_in[6];
    float* out = (float*)d_out;

    ushort* ws  = (ushort*)d_ws;
    ushort* qTp = ws;                                     // B*N*32 halves
    ushort* kTp = qTp + (size_t)BB * NN * 32;             // B*N*32 halves
    ushort* vtb = kTp + (size_t)BB * NN * 32;             // B*N*64 halves
    int* kmax = (int*)(vtb + (size_t)BB * NN * 64);       // B*8 (poison = neg int)

    qkv_kernel<<<320, 256, 0, stream>>>(x, Wq, bq, Wk, bk, Wv, bv, qTp, kTp, vtb, kmax);
    pack_kernel<<<256, 256, 0, stream>>>(vtb);
    attn_kernel<<<BB * 128, 512, 0, stream>>>(qTp, kTp, vtb, kmax, out);
}